// Round 1
// baseline (1326.424 us; speedup 1.0000x reference)
//
#include <hip/hip_runtime.h>

#define T_TOK 2048
#define DIM 2048
#define NE 16
#define NI 1408
#define TOPK 6

typedef __bf16 bf16x8 __attribute__((ext_vector_type(8)));
typedef float f32x4 __attribute__((ext_vector_type(4)));

static __device__ __forceinline__ unsigned short f2bf(float f) {
  unsigned int u = __builtin_bit_cast(unsigned int, f);
  u += 0x7fffu + ((u >> 16) & 1u);   // round-to-nearest-even
  return (unsigned short)(u >> 16);
}

static __device__ __forceinline__ void async_load16(const void* g, void* l) {
  __builtin_amdgcn_global_load_lds(
      (const __attribute__((address_space(1))) unsigned int*)g,
      (__attribute__((address_space(3))) unsigned int*)l, 16, 0, 0);
}

// ---------------- router: logits -> softmax -> top6 -> combine ----------------
__global__ void router_kernel(const float* __restrict__ x, const float* __restrict__ gw,
                              float* __restrict__ combine) {
  int t = blockIdx.x;
  int l = threadIdx.x;
  const float* xr = x + (size_t)t * DIM;
  float acc[NE];
#pragma unroll
  for (int e = 0; e < NE; e++) acc[e] = 0.f;
  for (int d = l; d < DIM; d += 64) {
    float xv = xr[d];
#pragma unroll
    for (int e = 0; e < NE; e++) acc[e] += xv * gw[e * DIM + d];
  }
#pragma unroll
  for (int e = 0; e < NE; e++) {
    float v = acc[e];
#pragma unroll
    for (int s = 32; s > 0; s >>= 1) v += __shfl_down(v, s, 64);
    acc[e] = v;
  }
  if (l == 0) {
    float mx = acc[0];
#pragma unroll
    for (int e = 1; e < NE; e++) mx = fmaxf(mx, acc[e]);
    float p[NE]; float sum = 0.f;
#pragma unroll
    for (int e = 0; e < NE; e++) { p[e] = expf(acc[e] - mx); sum += p[e]; }
    float inv = 1.f / sum;
#pragma unroll
    for (int e = 0; e < NE; e++) p[e] *= inv;
    float w[NE];
#pragma unroll
    for (int e = 0; e < NE; e++) w[e] = 0.f;
    int used = 0;
    float ssum = 0.f;
    for (int k = 0; k < TOPK; k++) {
      int best = 0; float bv = -1e30f;
      for (int e = 0; e < NE; e++) {
        if (!((used >> e) & 1) && acc[e] > bv) { bv = acc[e]; best = e; }
      }
      used |= (1 << best);
      w[best] = p[best];
      ssum += p[best];
    }
    float isum = 1.f / ssum;
    for (int e = 0; e < NE; e++) combine[t * NE + e] = w[e] * isum;
  }
}

// ---------------- cast fp32 -> bf16 (x and weight chunks) ----------------
__global__ void cast_x_kernel(const float* __restrict__ x, unsigned short* __restrict__ xb) {
  int i = (blockIdx.x * 256 + threadIdx.x) * 4;
  float4 v = *(const float4*)(x + i);
  ushort4 o = make_ushort4(f2bf(v.x), f2bf(v.y), f2bf(v.z), f2bf(v.w));
  *(ushort4*)(xb + i) = o;
}

__global__ void cast_w_kernel(const float* __restrict__ src, unsigned short* __restrict__ dst,
                              int n4) {
  int stride = gridDim.x * 256;
  for (int i = blockIdx.x * 256 + threadIdx.x; i < n4; i += stride) {
    float4 v = ((const float4*)src)[i];
    ushort4 o = make_ushort4(f2bf(v.x), f2bf(v.y), f2bf(v.z), f2bf(v.w));
    ((ushort4*)dst)[i] = o;
  }
}

// ---------------- per-expert token list building ----------------
__global__ void count_kernel(const float* __restrict__ combine, int* __restrict__ counts) {
  int e = blockIdx.x, l = threadIdx.x;
  int c = 0;
  for (int t0 = 0; t0 < T_TOK; t0 += 64) {
    bool pred = combine[(size_t)(t0 + l) * NE + e] > 0.f;
    unsigned long long m = __ballot(pred);
    c += (int)__popcll(m);
  }
  if (l == 0) counts[e] = c;
}

__global__ void scan_kernel(const int* __restrict__ counts, int* __restrict__ offsets) {
  if (threadIdx.x == 0) {
    int s = 0;
    for (int e = 0; e < NE; e++) { offsets[e] = s; s += counts[e]; }
    offsets[NE] = s;
  }
}

__global__ void fill_kernel(const float* __restrict__ combine, const int* __restrict__ offsets,
                            int* __restrict__ ids, float* __restrict__ scales) {
  int e = blockIdx.x, l = threadIdx.x;
  int base = offsets[e];
  for (int t0 = 0; t0 < T_TOK; t0 += 64) {
    int t = t0 + l;
    float w = combine[(size_t)t * NE + e];
    bool pred = w > 0.f;
    unsigned long long m = __ballot(pred);
    int idx = base + (int)__popcll(m & ((1ull << l) - 1ull));
    if (pred) { ids[idx] = t; scales[idx] = w; }
    base += (int)__popcll(m);
  }
}

// ======================================================================
// PRE-CAST PATH: weights already bf16 in wb; A and B both staged via
// global_load_lds width=16. LDS layout [chunk(8 cols)][row][16B] is
// byte-identical to the old ds_write layout, so fragment reads unchanged.
// ======================================================================

// GEMM1: h = silu(Xe @ W1g^T) * (Xe @ W1u^T). tile 128 tok x 64 i, BK=64.
__global__ __launch_bounds__(256) void gemm1_pre_kernel(
    const unsigned short* __restrict__ xb, const unsigned short* __restrict__ wb,
    const int* __restrict__ ids, const int* __restrict__ offsets,
    unsigned short* __restrict__ h, int e_base) {
  int ez = blockIdx.z;
  int e = e_base + ez;
  int off = offsets[e];
  int ne = offsets[e + 1] - off;
  int m0 = blockIdx.y * 128;
  if (m0 >= ne) return;
  int i0 = blockIdx.x * 64;

  __shared__ unsigned short At[8 * 128 * 8];   // 16 KB
  __shared__ unsigned short Bg[8 * 64 * 8];    // 8 KB
  __shared__ unsigned short Bu[8 * 64 * 8];    // 8 KB
  __shared__ int ids_l[128];

  int tid = threadIdx.x;
  int wave = tid >> 6, lane = tid & 63;

  if (tid < 128) {
    int s = m0 + tid;
    ids_l[tid] = (s < ne) ? ids[off + s] : 0;
  }
  __syncthreads();
  const unsigned short* a0 = xb + (size_t)ids_l[lane] * DIM;
  const unsigned short* a1 = xb + (size_t)ids_l[64 + lane] * DIM;
  const unsigned short* wg = wb + ((size_t)ez * (2 * NI) + i0 + lane) * DIM;
  const unsigned short* wu = wb + ((size_t)ez * (2 * NI) + NI + i0 + lane) * DIM;

  int wm = wave >> 1, wn = wave & 1;
  int quad = lane >> 4, l15 = lane & 15;

  f32x4 zf = {0.f, 0.f, 0.f, 0.f};
  f32x4 accg[4][2], accu[4][2];
#pragma unroll
  for (int a = 0; a < 4; a++)
#pragma unroll
    for (int b = 0; b < 2; b++) { accg[a][b] = zf; accu[a][b] = zf; }

  for (int k0 = 0; k0 < DIM; k0 += 64) {
    // A tile: 16 wave-loads total, 4 per wave
#pragma unroll
    for (int j = 0; j < 4; j++) {
      int linear = wave * 4 + j;
      int c = linear >> 1;
      int half = j & 1;             // wave*4 even
      async_load16((half ? a1 : a0) + k0 + c * 8, &At[c * 1024 + half * 512]);
    }
    // B tiles: bf16, 8 wave-loads each / 4 waves = 2 per wave per matrix
#pragma unroll
    for (int j = 0; j < 2; j++) {
      int c = wave * 2 + j;
      async_load16(wg + k0 + c * 8, &Bg[c * 512]);
      async_load16(wu + k0 + c * 8, &Bu[c * 512]);
    }
    __syncthreads();
#pragma unroll
    for (int ks = 0; ks < 2; ks++) {
      int cb = ks * 4 + quad;
      bf16x8 af[4], bgf[2], buf_[2];
#pragma unroll
      for (int mt = 0; mt < 4; mt++)
        af[mt] = *(const bf16x8*)&At[cb * 1024 + (wm * 64 + mt * 16 + l15) * 8];
#pragma unroll
      for (int nt = 0; nt < 2; nt++) {
        bgf[nt] = *(const bf16x8*)&Bg[cb * 512 + (wn * 32 + nt * 16 + l15) * 8];
        buf_[nt] = *(const bf16x8*)&Bu[cb * 512 + (wn * 32 + nt * 16 + l15) * 8];
      }
#pragma unroll
      for (int mt = 0; mt < 4; mt++)
#pragma unroll
        for (int nt = 0; nt < 2; nt++) {
          accg[mt][nt] = __builtin_amdgcn_mfma_f32_16x16x32_bf16(af[mt], bgf[nt], accg[mt][nt], 0, 0, 0);
          accu[mt][nt] = __builtin_amdgcn_mfma_f32_16x16x32_bf16(af[mt], buf_[nt], accu[mt][nt], 0, 0, 0);
        }
    }
    __syncthreads();
  }
#pragma unroll
  for (int mt = 0; mt < 4; mt++)
#pragma unroll
    for (int nt = 0; nt < 2; nt++)
#pragma unroll
      for (int r = 0; r < 4; r++) {
        int row_l = wm * 64 + mt * 16 + quad * 4 + r;
        if (m0 + row_l < ne) {
          float gv = accg[mt][nt][r];
          float uv = accu[mt][nt][r];
          float hv = gv * uv / (1.f + __expf(-gv));
          int col = i0 + wn * 32 + nt * 16 + l15;
          h[(size_t)(off + m0 + row_l) * NI + col] = f2bf(hv);
        }
      }
}

// GEMM2: out[t] += scale * (h_e @ W2^T). tile 128 tok x 128 d, BK=64, K=1408.
__global__ __launch_bounds__(256) void gemm2_pre_kernel(
    const unsigned short* __restrict__ h, const unsigned short* __restrict__ wb,
    const int* __restrict__ ids, const float* __restrict__ scales,
    const int* __restrict__ offsets, float* __restrict__ out, int e_base) {
  int ez = blockIdx.z;
  int e = e_base + ez;
  int off = offsets[e];
  int ne = offsets[e + 1] - off;
  int m0 = blockIdx.y * 128;
  if (m0 >= ne) return;
  int n0 = blockIdx.x * 128;

  __shared__ unsigned short At[8 * 128 * 8];   // 16 KB
  __shared__ unsigned short Bt[8 * 128 * 8];   // 16 KB
  __shared__ int ids_l[128];
  __shared__ float scl_l[128];

  int tid = threadIdx.x;
  int wave = tid >> 6, lane = tid & 63;
  if (tid < 128) {
    int s = m0 + tid;
    bool v = s < ne;
    ids_l[tid] = v ? ids[off + s] : 0;
    scl_l[tid] = v ? scales[off + s] : 0.f;
  }
  __syncthreads();

  const unsigned short* h0 = h + (size_t)(off + m0 + lane) * NI;        // h padded by 128 rows
  const unsigned short* h1 = h + (size_t)(off + m0 + 64 + lane) * NI;
  const unsigned short* b0 = wb + ((size_t)ez * DIM + n0 + lane) * NI;
  const unsigned short* b1 = b0 + (size_t)64 * NI;

  int wm = wave >> 1, wn = wave & 1;
  int quad = lane >> 4, l15 = lane & 15;

  f32x4 zf = {0.f, 0.f, 0.f, 0.f};
  f32x4 acc[4][4];
#pragma unroll
  for (int a = 0; a < 4; a++)
#pragma unroll
    for (int b = 0; b < 4; b++) acc[a][b] = zf;

  for (int k0 = 0; k0 < NI; k0 += 64) {
#pragma unroll
    for (int j = 0; j < 4; j++) {
      int linear = wave * 4 + j;
      int c = linear >> 1;
      int half = j & 1;
      async_load16((half ? h1 : h0) + k0 + c * 8, &At[c * 1024 + half * 512]);
      async_load16((half ? b1 : b0) + k0 + c * 8, &Bt[c * 1024 + half * 512]);
    }
    __syncthreads();
#pragma unroll
    for (int ks = 0; ks < 2; ks++) {
      int cb = ks * 4 + quad;
      bf16x8 af[4], bf[4];
#pragma unroll
      for (int mt = 0; mt < 4; mt++)
        af[mt] = *(const bf16x8*)&At[cb * 1024 + (wm * 64 + mt * 16 + l15) * 8];
#pragma unroll
      for (int nt = 0; nt < 4; nt++)
        bf[nt] = *(const bf16x8*)&Bt[cb * 1024 + (wn * 64 + nt * 16 + l15) * 8];
#pragma unroll
      for (int mt = 0; mt < 4; mt++)
#pragma unroll
        for (int nt = 0; nt < 4; nt++)
          acc[mt][nt] = __builtin_amdgcn_mfma_f32_16x16x32_bf16(af[mt], bf[nt], acc[mt][nt], 0, 0, 0);
    }
    __syncthreads();
  }
#pragma unroll
  for (int mt = 0; mt < 4; mt++)
#pragma unroll
    for (int nt = 0; nt < 4; nt++)
#pragma unroll
      for (int r = 0; r < 4; r++) {
        int row_l = wm * 64 + mt * 16 + quad * 4 + r;
        if (m0 + row_l < ne) {
          int t = ids_l[row_l];
          float s = scl_l[row_l];
          int col = n0 + wn * 64 + nt * 16 + l15;
          atomicAdd(&out[(size_t)t * DIM + col], s * acc[mt][nt][r]);
        }
      }
}

// ======================================================================
// FALLBACK PATH (ws too small for bf16 weight scratch): previous verified
// kernels, fp32 weights converted in-kernel.
// ======================================================================
__global__ __launch_bounds__(256) void gemm1_fb_kernel(
    const unsigned short* __restrict__ xb, const float* __restrict__ w13,
    const int* __restrict__ ids, const int* __restrict__ offsets,
    unsigned short* __restrict__ h) {
  int e = blockIdx.z;
  int off = offsets[e];
  int ne = offsets[e + 1] - off;
  int m0 = blockIdx.y * 128;
  if (m0 >= ne) return;
  int i0 = blockIdx.x * 64;

  __shared__ unsigned short At[8 * 128 * 8];
  __shared__ unsigned short Bg[8 * 64 * 8];
  __shared__ unsigned short Bu[8 * 64 * 8];
  __shared__ int ids_l[128];

  int tid = threadIdx.x;
  int wave = tid >> 6, lane = tid & 63;

  if (tid < 128) {
    int s = m0 + tid;
    ids_l[tid] = (s < ne) ? ids[off + s] : 0;
  }
  __syncthreads();
  int gid0 = ids_l[lane];
  int gid1 = ids_l[64 + lane];
  const unsigned short* a0 = xb + (size_t)gid0 * DIM;
  const unsigned short* a1 = xb + (size_t)gid1 * DIM;

  const float* We = w13 + (size_t)e * (2 * NI) * DIM;
  const float* Wg = We + (size_t)i0 * DIM;
  const float* Wu = We + (size_t)(NI + i0) * DIM;

  int wm = wave >> 1, wn = wave & 1;
  int quad = lane >> 4, l15 = lane & 15;

  f32x4 zf = {0.f, 0.f, 0.f, 0.f};
  f32x4 accg[4][2], accu[4][2];
#pragma unroll
  for (int a = 0; a < 4; a++)
#pragma unroll
    for (int b = 0; b < 2; b++) { accg[a][b] = zf; accu[a][b] = zf; }

  int brow = tid >> 4;
  int c4 = tid & 15;
  int bchunk = c4 >> 1;
  int hof = (c4 & 1) * 4;

  for (int k0 = 0; k0 < DIM; k0 += 64) {
#pragma unroll
    for (int j = 0; j < 4; j++) {
      int linear = wave * 4 + j;
      int chunk = linear >> 1;
      int half = j & 1;
      const unsigned short* src = (half ? a1 : a0) + k0 + chunk * 8;
      async_load16(src, &At[chunk * 1024 + half * 512]);
    }
#pragma unroll
    for (int r = 0; r < 4; r++) {
      int row = brow + r * 16;
      float4 vg = *(const float4*)(Wg + (size_t)row * DIM + k0 + c4 * 4);
      float4 vu = *(const float4*)(Wu + (size_t)row * DIM + k0 + c4 * 4);
      ushort4 og = make_ushort4(f2bf(vg.x), f2bf(vg.y), f2bf(vg.z), f2bf(vg.w));
      ushort4 ou = make_ushort4(f2bf(vu.x), f2bf(vu.y), f2bf(vu.z), f2bf(vu.w));
      *(ushort4*)&Bg[bchunk * 512 + row * 8 + hof] = og;
      *(ushort4*)&Bu[bchunk * 512 + row * 8 + hof] = ou;
    }
    __syncthreads();
#pragma unroll
    for (int ks = 0; ks < 2; ks++) {
      int cb = ks * 4 + quad;
      bf16x8 af[4], bgf[2], buf_[2];
#pragma unroll
      for (int mt = 0; mt < 4; mt++)
        af[mt] = *(const bf16x8*)&At[cb * 1024 + (wm * 64 + mt * 16 + l15) * 8];
#pragma unroll
      for (int nt = 0; nt < 2; nt++) {
        bgf[nt] = *(const bf16x8*)&Bg[cb * 512 + (wn * 32 + nt * 16 + l15) * 8];
        buf_[nt] = *(const bf16x8*)&Bu[cb * 512 + (wn * 32 + nt * 16 + l15) * 8];
      }
#pragma unroll
      for (int mt = 0; mt < 4; mt++)
#pragma unroll
        for (int nt = 0; nt < 2; nt++) {
          accg[mt][nt] = __builtin_amdgcn_mfma_f32_16x16x32_bf16(af[mt], bgf[nt], accg[mt][nt], 0, 0, 0);
          accu[mt][nt] = __builtin_amdgcn_mfma_f32_16x16x32_bf16(af[mt], buf_[nt], accu[mt][nt], 0, 0, 0);
        }
    }
    __syncthreads();
  }
#pragma unroll
  for (int mt = 0; mt < 4; mt++)
#pragma unroll
    for (int nt = 0; nt < 2; nt++)
#pragma unroll
      for (int r = 0; r < 4; r++) {
        int row_l = wm * 64 + mt * 16 + quad * 4 + r;
        if (m0 + row_l < ne) {
          float gv = accg[mt][nt][r];
          float uv = accu[mt][nt][r];
          float hv = gv * uv / (1.f + __expf(-gv));
          int col = i0 + wn * 32 + nt * 16 + l15;
          h[(size_t)(off + m0 + row_l) * NI + col] = f2bf(hv);
        }
      }
}

__global__ __launch_bounds__(256) void gemm2_fb_kernel(
    const unsigned short* __restrict__ h, const float* __restrict__ w2,
    const int* __restrict__ ids, const float* __restrict__ scales,
    const int* __restrict__ offsets, float* __restrict__ out) {
  int e = blockIdx.z;
  int off = offsets[e];
  int ne = offsets[e + 1] - off;
  int m0 = blockIdx.y * 128;
  if (m0 >= ne) return;
  int n0 = blockIdx.x * 128;

  __shared__ unsigned short At[8 * 128 * 8];
  __shared__ unsigned short Bt[8 * 128 * 8];
  __shared__ int ids_l[128];
  __shared__ float scl_l[128];

  int tid = threadIdx.x;
  int wave = tid >> 6, lane = tid & 63;
  if (tid < 128) {
    int s = m0 + tid;
    bool v = s < ne;
    ids_l[tid] = v ? ids[off + s] : 0;
    scl_l[tid] = v ? scales[off + s] : 0.f;
  }
  __syncthreads();

  const unsigned short* h0 = h + (size_t)(off + m0 + lane) * NI;
  const unsigned short* h1 = h + (size_t)(off + m0 + 64 + lane) * NI;
  const float* W = w2 + (size_t)e * DIM * NI;

  int wm = wave >> 1, wn = wave & 1;
  int quad = lane >> 4, l15 = lane & 15;

  f32x4 zf = {0.f, 0.f, 0.f, 0.f};
  f32x4 acc[4][4];
#pragma unroll
  for (int a = 0; a < 4; a++)
#pragma unroll
    for (int b = 0; b < 4; b++) acc[a][b] = zf;

  int brow = tid >> 4, c4 = tid & 15, bchunk = c4 >> 1, hof = (c4 & 1) * 4;

  for (int k0 = 0; k0 < NI; k0 += 64) {
#pragma unroll
    for (int j = 0; j < 4; j++) {
      int linear = wave * 4 + j;
      int chunk = linear >> 1;
      int half = j & 1;
      const unsigned short* src = (half ? h1 : h0) + k0 + chunk * 8;
      async_load16(src, &At[chunk * 1024 + half * 512]);
    }
#pragma unroll
    for (int r = 0; r < 8; r++) {
      int row = brow + r * 16;
      float4 v = *(const float4*)(W + (size_t)(n0 + row) * NI + k0 + c4 * 4);
      ushort4 o = make_ushort4(f2bf(v.x), f2bf(v.y), f2bf(v.z), f2bf(v.w));
      *(ushort4*)&Bt[bchunk * 1024 + row * 8 + hof] = o;
    }
    __syncthreads();
#pragma unroll
    for (int ks = 0; ks < 2; ks++) {
      int cb = ks * 4 + quad;
      bf16x8 af[4], bf[4];
#pragma unroll
      for (int mt = 0; mt < 4; mt++)
        af[mt] = *(const bf16x8*)&At[cb * 1024 + (wm * 64 + mt * 16 + l15) * 8];
#pragma unroll
      for (int nt = 0; nt < 4; nt++)
        bf[nt] = *(const bf16x8*)&Bt[cb * 1024 + (wn * 64 + nt * 16 + l15) * 8];
#pragma unroll
      for (int mt = 0; mt < 4; mt++)
#pragma unroll
        for (int nt = 0; nt < 4; nt++)
          acc[mt][nt] = __builtin_amdgcn_mfma_f32_16x16x32_bf16(af[mt], bf[nt], acc[mt][nt], 0, 0, 0);
    }
    __syncthreads();
  }
#pragma unroll
  for (int mt = 0; mt < 4; mt++)
#pragma unroll
    for (int nt = 0; nt < 4; nt++)
#pragma unroll
      for (int r = 0; r < 4; r++) {
        int row_l = wm * 64 + mt * 16 + quad * 4 + r;
        if (m0 + row_l < ne) {
          int t = ids_l[row_l];
          float s = scl_l[row_l];
          int col = n0 + wn * 64 + nt * 16 + l15;
          atomicAdd(&out[(size_t)t * DIM + col], s * acc[mt][nt][r]);
        }
      }
}

extern "C" void kernel_launch(void* const* d_in, const int* in_sizes, int n_in,
                              void* d_out, int out_size, void* d_ws, size_t ws_size,
                              hipStream_t stream) {
  const float* x   = (const float*)d_in[0];
  const float* gw  = (const float*)d_in[1];
  const float* w13 = (const float*)d_in[2];
  const float* w2  = (const float*)d_in[3];
  float* out = (float*)d_out;

  char* ws = (char*)d_ws;
  // ws layout (bytes):
  //   combine  @ 0x000000   2048*16*4 = 131072
  //   counts   @ 0x020000   64
  //   offsets  @ 0x020100   68
  //   ids      @ 0x020200   12288*4 = 49152
  //   scales   @ 0x02D000   12288*4 = 49152
  //   x_bf16   @ 0x040000   2048*2048*2 = 8388608
  //   h        @ 0x840000   (12288+128)*1408*2 = 34963456   (padded rows)
  //   wb       @ 0x2A00000  bf16 weight scratch, chunk*2816*2048*2 (optional)
  float* combine        = (float*)(ws + 0x000000);
  int* counts           = (int*)  (ws + 0x020000);
  int* offsets          = (int*)  (ws + 0x020100);
  int* ids              = (int*)  (ws + 0x020200);
  float* scales         = (float*)(ws + 0x02D000);
  unsigned short* xb    = (unsigned short*)(ws + 0x040000);
  unsigned short* h     = (unsigned short*)(ws + 0x840000);
  unsigned short* wb    = (unsigned short*)(ws + 0x2A00000);

  const size_t wb_off = 0x2A00000;
  const size_t per_e13 = (size_t)(2 * NI) * DIM * 2;   // bf16 bytes per expert, w13
  int chunk = 0;
  if      (ws_size >= wb_off + 8 * per_e13) chunk = 8;
  else if (ws_size >= wb_off + 4 * per_e13) chunk = 4;
  else if (ws_size >= wb_off + 2 * per_e13) chunk = 2;

  hipMemsetAsync(d_out, 0, (size_t)T_TOK * DIM * sizeof(float), stream);

  router_kernel<<<T_TOK, 64, 0, stream>>>(x, gw, combine);
  cast_x_kernel<<<(T_TOK * DIM) / (256 * 4), 256, 0, stream>>>(x, xb);
  count_kernel<<<NE, 64, 0, stream>>>(combine, counts);
  scan_kernel<<<1, 64, 0, stream>>>(counts, offsets);
  fill_kernel<<<NE, 64, 0, stream>>>(combine, offsets, ids, scales);

  if (chunk) {
    // GEMM1 in expert batches: cast w13 chunk -> wb (stream-serialized reuse)
    for (int b = 0; b < NE; b += chunk) {
      int n4 = chunk * 2 * NI * DIM / 4;
      cast_w_kernel<<<2048, 256, 0, stream>>>(w13 + (size_t)b * (2 * NI) * DIM, wb, n4);
      gemm1_pre_kernel<<<dim3(NI / 64, T_TOK / 128, chunk), 256, 0, stream>>>(
          xb, wb, ids, offsets, h, b);
    }
    // GEMM2 in expert batches: cast w2 chunk -> wb (aliases w13 scratch; safe,
    // all launches on one stream)
    for (int b = 0; b < NE; b += chunk) {
      int n4 = chunk * DIM * NI / 4;
      cast_w_kernel<<<2048, 256, 0, stream>>>(w2 + (size_t)b * DIM * NI, wb, n4);
      gemm2_pre_kernel<<<dim3(DIM / 128, T_TOK / 128, chunk), 256, 0, stream>>>(
          h, wb, ids, scales, offsets, out, b);
    }
  } else {
    gemm1_fb_kernel<<<dim3(NI / 64, T_TOK / 128, NE), 256, 0, stream>>>(xb, w13, ids, offsets, h);
    gemm2_fb_kernel<<<dim3(DIM / 128, T_TOK / 128, NE), 256, 0, stream>>>(h, w2, ids, scales, offsets, out);
  }
}

// Round 2
// 1199.270 us; speedup vs baseline: 1.1060x; 1.1060x over previous
//
#include <hip/hip_runtime.h>

#define T_TOK 2048
#define DIM 2048
#define NE 16
#define NI 1408
#define TOPK 6

typedef __bf16 bf16x8 __attribute__((ext_vector_type(8)));
typedef float f32x4 __attribute__((ext_vector_type(4)));

static __device__ __forceinline__ unsigned short f2bf(float f) {
  unsigned int u = __builtin_bit_cast(unsigned int, f);
  u += 0x7fffu + ((u >> 16) & 1u);   // round-to-nearest-even
  return (unsigned short)(u >> 16);
}

static __device__ __forceinline__ void async_load16(const void* g, void* l) {
  __builtin_amdgcn_global_load_lds(
      (const __attribute__((address_space(1))) unsigned int*)g,
      (__attribute__((address_space(3))) unsigned int*)l, 16, 0, 0);
}

// ---------------- router: logits -> softmax -> top6 -> combine ----------------
__global__ void router_kernel(const float* __restrict__ x, const float* __restrict__ gw,
                              float* __restrict__ combine) {
  int t = blockIdx.x;
  int l = threadIdx.x;
  const float* xr = x + (size_t)t * DIM;
  float acc[NE];
#pragma unroll
  for (int e = 0; e < NE; e++) acc[e] = 0.f;
  for (int d = l; d < DIM; d += 64) {
    float xv = xr[d];
#pragma unroll
    for (int e = 0; e < NE; e++) acc[e] += xv * gw[e * DIM + d];
  }
#pragma unroll
  for (int e = 0; e < NE; e++) {
    float v = acc[e];
#pragma unroll
    for (int s = 32; s > 0; s >>= 1) v += __shfl_down(v, s, 64);
    acc[e] = v;
  }
  if (l == 0) {
    float mx = acc[0];
#pragma unroll
    for (int e = 1; e < NE; e++) mx = fmaxf(mx, acc[e]);
    float p[NE]; float sum = 0.f;
#pragma unroll
    for (int e = 0; e < NE; e++) { p[e] = expf(acc[e] - mx); sum += p[e]; }
    float inv = 1.f / sum;
#pragma unroll
    for (int e = 0; e < NE; e++) p[e] *= inv;
    float w[NE];
#pragma unroll
    for (int e = 0; e < NE; e++) w[e] = 0.f;
    int used = 0;
    float ssum = 0.f;
    for (int k = 0; k < TOPK; k++) {
      int best = 0; float bv = -1e30f;
      for (int e = 0; e < NE; e++) {
        if (!((used >> e) & 1) && acc[e] > bv) { bv = acc[e]; best = e; }
      }
      used |= (1 << best);
      w[best] = p[best];
      ssum += p[best];
    }
    float isum = 1.f / ssum;
    for (int e = 0; e < NE; e++) combine[t * NE + e] = w[e] * isum;
  }
}

// ---------------- cast hidden_states to bf16 ----------------
__global__ void cast_x_kernel(const float* __restrict__ x, unsigned short* __restrict__ xb) {
  int i = (blockIdx.x * 256 + threadIdx.x) * 4;
  float4 v = *(const float4*)(x + i);
  ushort4 o = make_ushort4(f2bf(v.x), f2bf(v.y), f2bf(v.z), f2bf(v.w));
  *(ushort4*)(xb + i) = o;
}

// ---------------- per-expert token list building ----------------
__global__ void count_kernel(const float* __restrict__ combine, int* __restrict__ counts) {
  int e = blockIdx.x, l = threadIdx.x;
  int c = 0;
  for (int t0 = 0; t0 < T_TOK; t0 += 64) {
    bool pred = combine[(size_t)(t0 + l) * NE + e] > 0.f;
    unsigned long long m = __ballot(pred);
    c += (int)__popcll(m);
  }
  if (l == 0) counts[e] = c;
}

__global__ void scan_kernel(const int* __restrict__ counts, int* __restrict__ offsets) {
  if (threadIdx.x == 0) {
    int s = 0;
    for (int e = 0; e < NE; e++) { offsets[e] = s; s += counts[e]; }
    offsets[NE] = s;
  }
}

__global__ void fill_kernel(const float* __restrict__ combine, const int* __restrict__ offsets,
                            int* __restrict__ ids, float* __restrict__ scales) {
  int e = blockIdx.x, l = threadIdx.x;
  int base = offsets[e];
  for (int t0 = 0; t0 < T_TOK; t0 += 64) {
    int t = t0 + l;
    float w = combine[(size_t)t * NE + e];
    bool pred = w > 0.f;
    unsigned long long m = __ballot(pred);
    int idx = base + (int)__popcll(m & ((1ull << l) - 1ull));
    if (pred) { ids[idx] = t; scales[idx] = w; }
    base += (int)__popcll(m);
  }
}

// ======================================================================
// GEMM1: h = silu(Xe @ W1g^T) * (Xe @ W1u^T), bf16 out.
// tile 128 tok x 64 i, BK=64, double-buffered prefetch (T3-min), fused
// fp32->bf16 B staging with XOR-swizzled ds_write, XCD-swizzled 1-D grid.
// ======================================================================
__global__ __launch_bounds__(256) void gemm1_kernel(
    const unsigned short* __restrict__ xb, const float* __restrict__ w13,
    const int* __restrict__ ids, const int* __restrict__ offsets,
    unsigned short* __restrict__ h) {
  // bijective XCD swizzle (nwg = 5632, %8 == 0): each XCD gets a contiguous
  // range of lin; token tile (iy) fastest so weight-panel sharers are adjacent.
  int bid = blockIdx.x;
  int lin = (bid & 7) * (5632 >> 3) + (bid >> 3);
  int iy = lin & 15;
  int ix = (lin >> 4) % 22;
  int e  = lin / 352;

  int off = offsets[e];
  int ne = offsets[e + 1] - off;
  int m0 = iy * 128;
  if (m0 >= ne) return;
  int i0 = ix * 64;

  __shared__ unsigned short At[2][8 * 128 * 8];   // 2 x 16 KB, [chunk][row128][16B]
  __shared__ unsigned short Bg[2][8 * 64 * 8];    // 2 x 8 KB,  [chunk][row64][16B]
  __shared__ unsigned short Bu[2][8 * 64 * 8];
  __shared__ int ids_l[128];

  int tid = threadIdx.x;
  int wave = tid >> 6, lane = tid & 63;

  if (tid < 128) {
    int s = m0 + tid;
    ids_l[tid] = (s < ne) ? ids[off + s] : 0;   // clamp partial tiles
  }
  __syncthreads();
  const unsigned short* a0 = xb + (size_t)ids_l[lane] * DIM;
  const unsigned short* a1 = xb + (size_t)ids_l[64 + lane] * DIM;

  const float* We = w13 + (size_t)e * (2 * NI) * DIM;
  const float* Wg = We + (size_t)i0 * DIM;
  const float* Wu = We + (size_t)(NI + i0) * DIM;

  int wm = wave >> 1, wn = wave & 1;
  int quad = lane >> 4, l15 = lane & 15;

  int brow = tid >> 4;          // 0..15
  int c4 = tid & 15;            // 16B col group
  int bchunk = c4 >> 1;         // 0..7
  int hof2 = (c4 & 1) * 8;      // byte offset within 16B slot

  f32x4 zf = {0.f, 0.f, 0.f, 0.f};
  f32x4 accg[4][2], accu[4][2];
#pragma unroll
  for (int a = 0; a < 4; a++)
#pragma unroll
    for (int b = 0; b < 2; b++) { accg[a][b] = zf; accu[a][b] = zf; }

#define G1_STAGE_A(P, K0)                                                      \
  _Pragma("unroll") for (int j = 0; j < 4; j++) {                              \
    int c = (wave * 4 + j) >> 1;                                               \
    int half = j & 1;                                                          \
    async_load16((half ? a1 : a0) + (K0) + c * 8, &At[P][c * 1024 + half * 512]); \
  }

#define G1_LOAD_B(K0)                                                          \
  _Pragma("unroll") for (int r = 0; r < 4; r++) {                              \
    int row = brow + r * 16;                                                   \
    vg[r] = *(const float4*)(Wg + (size_t)row * DIM + (K0) + c4 * 4);          \
    vu[r] = *(const float4*)(Wu + (size_t)row * DIM + (K0) + c4 * 4);          \
  }

#define G1_WRITE_B(P)                                                          \
  _Pragma("unroll") for (int r = 0; r < 4; r++) {                              \
    int row = brow + r * 16;                                                   \
    int swz = (bchunk * 1024 + row * 16 + hof2) ^ (bchunk << 4);               \
    ushort4 og = make_ushort4(f2bf(vg[r].x), f2bf(vg[r].y), f2bf(vg[r].z), f2bf(vg[r].w)); \
    ushort4 ou = make_ushort4(f2bf(vu[r].x), f2bf(vu[r].y), f2bf(vu[r].z), f2bf(vu[r].w)); \
    *(ushort4*)((char*)&Bg[P][0] + swz) = og;                                  \
    *(ushort4*)((char*)&Bu[P][0] + swz) = ou;                                  \
  }

#define G1_COMPUTE(P)                                                          \
  _Pragma("unroll") for (int ks = 0; ks < 2; ks++) {                           \
    int cb = ks * 4 + quad;                                                    \
    int cbx = cb << 4;                                                         \
    bf16x8 af[4], bgf[2], buf_[2];                                             \
    const char* Ab = (const char*)&At[P][0];                                   \
    const char* Bgb = (const char*)&Bg[P][0];                                  \
    const char* Bub = (const char*)&Bu[P][0];                                  \
    _Pragma("unroll") for (int mt = 0; mt < 4; mt++)                           \
      af[mt] = *(const bf16x8*)(Ab + cb * 2048 + (wm * 64 + mt * 16 + l15) * 16); \
    _Pragma("unroll") for (int nt = 0; nt < 2; nt++) {                         \
      int rb = cb * 1024 + (wn * 32 + nt * 16 + l15) * 16;                     \
      bgf[nt] = *(const bf16x8*)(Bgb + (rb ^ cbx));                            \
      buf_[nt] = *(const bf16x8*)(Bub + (rb ^ cbx));                           \
    }                                                                          \
    _Pragma("unroll") for (int mt = 0; mt < 4; mt++)                           \
      _Pragma("unroll") for (int nt = 0; nt < 2; nt++) {                       \
        accg[mt][nt] = __builtin_amdgcn_mfma_f32_16x16x32_bf16(af[mt], bgf[nt], accg[mt][nt], 0, 0, 0); \
        accu[mt][nt] = __builtin_amdgcn_mfma_f32_16x16x32_bf16(af[mt], buf_[nt], accu[mt][nt], 0, 0, 0); \
      }                                                                        \
  }

  // prologue: fill buf 0
  {
    float4 vg[4], vu[4];
    G1_STAGE_A(0, 0)
    G1_LOAD_B(0)
    G1_WRITE_B(0)
  }
  __syncthreads();

  int p = 0;
  for (int t = 0; t < DIM / 64 - 1; t++) {
    int k1 = (t + 1) * 64;
    float4 vg[4], vu[4];
    G1_STAGE_A(p ^ 1, k1)      // async global->LDS, lands during compute
    G1_LOAD_B(k1)              // fp32 -> regs, consumed after compute
    G1_COMPUTE(p)
    G1_WRITE_B(p ^ 1)          // cvt + ds_write into other buffer
    __syncthreads();
    p ^= 1;
  }
  G1_COMPUTE(p)

  // epilogue: h = silu(g) * u, store bf16
#pragma unroll
  for (int mt = 0; mt < 4; mt++)
#pragma unroll
    for (int nt = 0; nt < 2; nt++)
#pragma unroll
      for (int r = 0; r < 4; r++) {
        int row_l = wm * 64 + mt * 16 + quad * 4 + r;
        if (m0 + row_l < ne) {
          float gv = accg[mt][nt][r];
          float uv = accu[mt][nt][r];
          float hv = gv * uv / (1.f + __expf(-gv));
          int col = i0 + wn * 32 + nt * 16 + l15;
          h[(size_t)(off + m0 + row_l) * NI + col] = f2bf(hv);
        }
      }
#undef G1_STAGE_A
#undef G1_LOAD_B
#undef G1_WRITE_B
#undef G1_COMPUTE
}

// ======================================================================
// GEMM2: out[t] += scale * (h_e @ W2^T). tile 128 tok x 128 d, BK=64,
// K=1408. Same dbuf-prefetch + swizzled staging structure.
// ======================================================================
__global__ __launch_bounds__(256) void gemm2_kernel(
    const unsigned short* __restrict__ h, const float* __restrict__ w2,
    const int* __restrict__ ids, const float* __restrict__ scales,
    const int* __restrict__ offsets, float* __restrict__ out) {
  int bid = blockIdx.x;                       // nwg = 4096
  int lin = (bid & 7) * (4096 >> 3) + (bid >> 3);
  int iy = lin & 15;
  int ix = (lin >> 4) & 15;
  int e  = lin >> 8;

  int off = offsets[e];
  int ne = offsets[e + 1] - off;
  int m0 = iy * 128;
  if (m0 >= ne) return;
  int n0 = ix * 128;

  __shared__ unsigned short At[2][8 * 128 * 8];   // 2 x 16 KB
  __shared__ unsigned short Bt[2][8 * 128 * 8];   // 2 x 16 KB
  __shared__ int ids_l[128];
  __shared__ float scl_l[128];

  int tid = threadIdx.x;
  int wave = tid >> 6, lane = tid & 63;
  if (tid < 128) {
    int s = m0 + tid;
    bool v = s < ne;
    ids_l[tid] = v ? ids[off + s] : 0;
    scl_l[tid] = v ? scales[off + s] : 0.f;
  }
  __syncthreads();

  const unsigned short* h0 = h + (size_t)(off + m0 + lane) * NI;   // h padded rows
  const unsigned short* h1 = h + (size_t)(off + m0 + 64 + lane) * NI;
  const float* W = w2 + (size_t)e * DIM * NI + (size_t)n0 * NI;

  int wm = wave >> 1, wn = wave & 1;
  int quad = lane >> 4, l15 = lane & 15;

  int brow = tid >> 4;
  int c4 = tid & 15;
  int bchunk = c4 >> 1;
  int hof2 = (c4 & 1) * 8;

  f32x4 zf = {0.f, 0.f, 0.f, 0.f};
  f32x4 acc[4][4];
#pragma unroll
  for (int a = 0; a < 4; a++)
#pragma unroll
    for (int b = 0; b < 4; b++) acc[a][b] = zf;

#define G2_STAGE_A(P, K0)                                                      \
  _Pragma("unroll") for (int j = 0; j < 4; j++) {                              \
    int c = (wave * 4 + j) >> 1;                                               \
    int half = j & 1;                                                          \
    async_load16((half ? h1 : h0) + (K0) + c * 8, &At[P][c * 1024 + half * 512]); \
  }

#define G2_LOAD_B(K0)                                                          \
  _Pragma("unroll") for (int r = 0; r < 8; r++) {                              \
    int row = brow + r * 16;                                                   \
    vb[r] = *(const float4*)(W + (size_t)row * NI + (K0) + c4 * 4);            \
  }

#define G2_WRITE_B(P)                                                          \
  _Pragma("unroll") for (int r = 0; r < 8; r++) {                              \
    int row = brow + r * 16;                                                   \
    int swz = (bchunk * 2048 + row * 16 + hof2) ^ (bchunk << 4);               \
    ushort4 o = make_ushort4(f2bf(vb[r].x), f2bf(vb[r].y), f2bf(vb[r].z), f2bf(vb[r].w)); \
    *(ushort4*)((char*)&Bt[P][0] + swz) = o;                                   \
  }

#define G2_COMPUTE(P)                                                          \
  _Pragma("unroll") for (int ks = 0; ks < 2; ks++) {                           \
    int cb = ks * 4 + quad;                                                    \
    int cbx = cb << 4;                                                         \
    bf16x8 af[4], bf[4];                                                       \
    const char* Ab = (const char*)&At[P][0];                                   \
    const char* Bb = (const char*)&Bt[P][0];                                   \
    _Pragma("unroll") for (int mt = 0; mt < 4; mt++)                           \
      af[mt] = *(const bf16x8*)(Ab + cb * 2048 + (wm * 64 + mt * 16 + l15) * 16); \
    _Pragma("unroll") for (int nt = 0; nt < 4; nt++) {                         \
      int rb = cb * 2048 + (wn * 64 + nt * 16 + l15) * 16;                     \
      bf[nt] = *(const bf16x8*)(Bb + (rb ^ cbx));                              \
    }                                                                          \
    _Pragma("unroll") for (int mt = 0; mt < 4; mt++)                           \
      _Pragma("unroll") for (int nt = 0; nt < 4; nt++)                         \
        acc[mt][nt] = __builtin_amdgcn_mfma_f32_16x16x32_bf16(af[mt], bf[nt], acc[mt][nt], 0, 0, 0); \
  }

  {
    float4 vb[8];
    G2_STAGE_A(0, 0)
    G2_LOAD_B(0)
    G2_WRITE_B(0)
  }
  __syncthreads();

  int p = 0;
  for (int t = 0; t < NI / 64 - 1; t++) {
    int k1 = (t + 1) * 64;
    float4 vb[8];
    G2_STAGE_A(p ^ 1, k1)
    G2_LOAD_B(k1)
    G2_COMPUTE(p)
    G2_WRITE_B(p ^ 1)
    __syncthreads();
    p ^= 1;
  }
  G2_COMPUTE(p)

#pragma unroll
  for (int mt = 0; mt < 4; mt++)
#pragma unroll
    for (int nt = 0; nt < 4; nt++)
#pragma unroll
      for (int r = 0; r < 4; r++) {
        int row_l = wm * 64 + mt * 16 + quad * 4 + r;
        if (m0 + row_l < ne) {
          int t = ids_l[row_l];
          float s = scl_l[row_l];
          int col = n0 + wn * 64 + nt * 16 + l15;
          atomicAdd(&out[(size_t)t * DIM + col], s * acc[mt][nt][r]);
        }
      }
#undef G2_STAGE_A
#undef G2_LOAD_B
#undef G2_WRITE_B
#undef G2_COMPUTE
}

extern "C" void kernel_launch(void* const* d_in, const int* in_sizes, int n_in,
                              void* d_out, int out_size, void* d_ws, size_t ws_size,
                              hipStream_t stream) {
  const float* x   = (const float*)d_in[0];
  const float* gw  = (const float*)d_in[1];
  const float* w13 = (const float*)d_in[2];
  const float* w2  = (const float*)d_in[3];
  float* out = (float*)d_out;

  char* ws = (char*)d_ws;
  // ws layout (bytes):
  //   combine  @ 0x000000  2048*16*4 = 131072
  //   counts   @ 0x020000  64
  //   offsets  @ 0x020100  68
  //   ids      @ 0x020200  12288*4 = 49152
  //   scales   @ 0x02D000  12288*4 = 49152
  //   x_bf16   @ 0x040000  2048*2048*2 = 8388608
  //   h        @ 0x840000  (12288+128)*1408*2 = 34963456   (padded rows)
  float* combine        = (float*)(ws + 0x000000);
  int* counts           = (int*)  (ws + 0x020000);
  int* offsets          = (int*)  (ws + 0x020100);
  int* ids              = (int*)  (ws + 0x020200);
  float* scales         = (float*)(ws + 0x02D000);
  unsigned short* xb    = (unsigned short*)(ws + 0x040000);
  unsigned short* h     = (unsigned short*)(ws + 0x840000);

  hipMemsetAsync(d_out, 0, (size_t)T_TOK * DIM * sizeof(float), stream);

  router_kernel<<<T_TOK, 64, 0, stream>>>(x, gw, combine);
  cast_x_kernel<<<(T_TOK * DIM) / (256 * 4), 256, 0, stream>>>(x, xb);
  count_kernel<<<NE, 64, 0, stream>>>(combine, counts);
  scan_kernel<<<1, 64, 0, stream>>>(counts, offsets);
  fill_kernel<<<NE, 64, 0, stream>>>(combine, offsets, ids, scales);

  gemm1_kernel<<<16 * 22 * 16, 256, 0, stream>>>(xb, w13, ids, offsets, h);
  gemm2_kernel<<<16 * 16 * 16, 256, 0, stream>>>(h, w2, ids, scales, offsets, out);
}